// Round 1
// baseline (2545.997 us; speedup 1.0000x reference)
//
#include <hip/hip_runtime.h>
#include <math.h>

#define C_DIM  512   // channels (K of the dot product)
#define N_DICT 512   // dictionary rows
#define HW     4096  // 64*64 pixels per image
#define NCHUNK 128   // dict rows per wave (4 waves cover 512)
#define KCHUNK 16    // K-step per iteration

// inv_norm[n] = 1 / sqrt(sum_c dict[n][c]^2)  -- fp32, sqrt+div precision
__global__ __launch_bounds__(64) void dict_inv_norm(const float* __restrict__ dict,
                                                    float* __restrict__ inv_norm) {
    const int n = blockIdx.x;
    const int lane = threadIdx.x;
    const float* row = dict + n * C_DIM;
    float s = 0.f;
#pragma unroll
    for (int j = 0; j < C_DIM / 64; ++j) {
        float v = row[j * 64 + lane];
        s = fmaf(v, v, s);
    }
#pragma unroll
    for (int off = 32; off > 0; off >>= 1)
        s += __shfl_down(s, off, 64);
    if (lane == 0) inv_norm[n] = 1.0f / sqrtf(s);
}

// Main fused kernel: scores + argmax + thresholded gather-write.
// Block = 256 thr = 4 waves over one 64-pixel group; wave w owns dict rows
// [128w, 128w+128). lane = pixel -> coalesced x loads; dict via uniform
// scalar loads broadcast into v_fmac (FMA-issue-bound by design).
__global__ __launch_bounds__(256, 2) void negdict_main(const float* __restrict__ x,
                                                       const float* __restrict__ dict,
                                                       const float* __restrict__ inv_norm,
                                                       float* __restrict__ out) {
    const int pg   = blockIdx.x;          // 0..1023
    const int b    = pg >> 6;             // batch
    const int pix0 = (pg & 63) << 6;      // pixel group base within image
    const int lane = (int)(threadIdx.x & 63);
    const int wv   = __builtin_amdgcn_readfirstlane((int)(threadIdx.x >> 6)); // uniform wave id
    const int pix  = pix0 + lane;
    const int n0   = wv * NCHUNK;

    const float* __restrict__ xb = x + (size_t)b * C_DIM * HW; // [C][HW]

    float acc[NCHUNK];
#pragma unroll
    for (int i = 0; i < NCHUNK; ++i) acc[i] = 0.f;

    float sumsq = 0.f;

    for (int kc = 0; kc < C_DIM; kc += KCHUNK) {
        float xk[KCHUNK];
#pragma unroll
        for (int j = 0; j < KCHUNK; ++j)
            xk[j] = xb[(size_t)(kc + j) * HW + pix];   // coalesced (lane = pixel)
#pragma unroll
        for (int j = 0; j < KCHUNK; ++j)
            sumsq = fmaf(xk[j], xk[j], sumsq);

#pragma unroll
        for (int i = 0; i < NCHUNK; ++i) {
            const float* __restrict__ drow = dict + (size_t)(n0 + i) * C_DIM + kc; // uniform addr
#pragma unroll
            for (int j = 0; j < KCHUNK; ++j)
                acc[i] = fmaf(drow[j], xk[j], acc[i]); // v_fmac_f32 acc, s, v
        }
    }

    // per-wave argmax over its 128 rows (ascending n, strict > => first-min ties like np.argmin)
    float best = -3.0e38f;
    int   bestn = n0;
#pragma unroll
    for (int i = 0; i < NCHUNK; ++i) {
        float s = acc[i] * inv_norm[n0 + i];
        if (s > best) { best = s; bestn = n0 + i; }
    }

    // cross-wave combine (n ranges ascend with wave id -> tie keeps lowest n)
    __shared__ float ls_best[4][64];
    __shared__ int   ls_idx[4][64];
    ls_best[wv][lane] = best;
    ls_idx[wv][lane]  = bestn;
    __syncthreads();

    float fbest = ls_best[0][lane];
    int   fidx  = ls_idx[0][lane];
#pragma unroll
    for (int q = 1; q < 4; ++q) {
        float v  = ls_best[q][lane];
        int   id = ls_idx[q][lane];
        if (v > fbest) { fbest = v; fidx = id; }
    }

    // apm < 0.625  <=>  sim_max > -0.25  <=>  g_max > -0.25 * ||x||
    const bool replace = fbest > (-0.25f * sqrtf(sumsq));
    const unsigned long long need_x = __ballot(!replace); // almost always 0

    float* __restrict__ ob = out + (size_t)b * C_DIM * HW;
    const float* __restrict__ drow = dict + (size_t)fidx * C_DIM;

    const int c0 = wv * (C_DIM / 4);   // wave w writes channels [128w, 128w+128)
#pragma unroll 8
    for (int c = c0; c < c0 + C_DIM / 4; ++c) {
        float v = drow[c];             // gather, L2-hot (dict = 1 MB)
        if (need_x) {
            float xv = xb[(size_t)c * HW + pix];
            if (!replace) v = xv;
        }
        ob[(size_t)c * HW + pix] = v;  // coalesced store
    }
}

extern "C" void kernel_launch(void* const* d_in, const int* in_sizes, int n_in,
                              void* d_out, int out_size, void* d_ws, size_t ws_size,
                              hipStream_t stream) {
    const float* x    = (const float*)d_in[0];
    const float* dict = (const float*)d_in[1];
    float* out        = (float*)d_out;
    float* inv_norm   = (float*)d_ws;  // 512 floats of scratch

    dict_inv_norm<<<N_DICT, 64, 0, stream>>>(dict, inv_norm);
    negdict_main<<<1024, 256, 0, stream>>>(x, dict, inv_norm, out);
}

// Round 2
// 1655.973 us; speedup vs baseline: 1.5375x; 1.5375x over previous
//
#include <hip/hip_runtime.h>
#include <math.h>

#define C_DIM  512   // channels (K of the dot product)
#define N_DICT 512   // dictionary rows
#define HW     4096  // 64*64 pixels per image
#define NROWS  64    // dict rows per wave (8 waves cover 512)
#define KCHUNK 16    // K-step per iteration

// inv_norm[n] = 1 / sqrt(sum_c dict[n][c]^2)  -- fp32, sqrt+div precision
__global__ __launch_bounds__(64) void dict_inv_norm(const float* __restrict__ dict,
                                                    float* __restrict__ inv_norm) {
    const int n = blockIdx.x;
    const int lane = threadIdx.x;
    const float* row = dict + n * C_DIM;
    float s = 0.f;
#pragma unroll
    for (int j = 0; j < C_DIM / 64; ++j) {
        float v = row[j * 64 + lane];
        s = fmaf(v, v, s);
    }
#pragma unroll
    for (int off = 32; off > 0; off >>= 1)
        s += __shfl_down(s, off, 64);
    if (lane == 0) inv_norm[n] = 1.0f / sqrtf(s);
}

// Block = 512 thr = 8 waves over one 64-pixel group; wave w owns dict rows
// [64w, 64w+64) -> only 64 fp32 accumulators per lane (round-1's 128 spilled:
// VGPR_Count=88, FETCH 93GB of scratch traffic). lane = pixel -> coalesced x
// loads; dict rows are wave-uniform -> scalar loads broadcast into v_fmac.
__global__ __launch_bounds__(512, 4) void negdict_main(const float* __restrict__ x,
                                                       const float* __restrict__ dict,
                                                       const float* __restrict__ inv_norm,
                                                       float* __restrict__ out) {
    const int pg   = blockIdx.x;          // 0..1023
    const int b    = pg >> 6;             // batch
    const int pix0 = (pg & 63) << 6;      // pixel group base within image
    const int lane = (int)(threadIdx.x & 63);
    const int wv   = __builtin_amdgcn_readfirstlane((int)(threadIdx.x >> 6)); // uniform wave id 0..7
    const int pix  = pix0 + lane;
    const int n0   = wv * NROWS;

    const float* __restrict__ xb = x + (size_t)b * C_DIM * HW; // [C][HW]

    float acc[NROWS];
#pragma unroll
    for (int i = 0; i < NROWS; ++i) acc[i] = 0.f;

    float sumsq = 0.f;

    for (int kc = 0; kc < C_DIM; kc += KCHUNK) {
        float xk[KCHUNK];
#pragma unroll
        for (int j = 0; j < KCHUNK; ++j)
            xk[j] = xb[(size_t)(kc + j) * HW + pix];   // coalesced (lane = pixel)
#pragma unroll
        for (int j = 0; j < KCHUNK; ++j)
            sumsq = fmaf(xk[j], xk[j], sumsq);

#pragma unroll
        for (int i = 0; i < NROWS; ++i) {
            const float* __restrict__ drow = dict + (size_t)(n0 + i) * C_DIM + kc; // uniform addr
#pragma unroll
            for (int j = 0; j < KCHUNK; ++j)
                acc[i] = fmaf(drow[j], xk[j], acc[i]); // v_fmac_f32 acc, s_broadcast, v
        }
    }

    // per-wave argmax over its 64 rows (ascending n, strict > => first-min ties like np.argmin)
    float best = -3.0e38f;
    int   bestn = n0;
#pragma unroll
    for (int i = 0; i < NROWS; ++i) {
        float s = acc[i] * inv_norm[n0 + i];
        if (s > best) { best = s; bestn = n0 + i; }
    }

    // cross-wave combine (n ranges ascend with wave id -> tie keeps lowest n)
    __shared__ float ls_best[8][64];
    __shared__ int   ls_idx[8][64];
    ls_best[wv][lane] = best;
    ls_idx[wv][lane]  = bestn;
    __syncthreads();

    float fbest = ls_best[0][lane];
    int   fidx  = ls_idx[0][lane];
#pragma unroll
    for (int q = 1; q < 8; ++q) {
        float v  = ls_best[q][lane];
        int   id = ls_idx[q][lane];
        if (v > fbest) { fbest = v; fidx = id; }
    }

    // apm < 0.625  <=>  sim_max > -0.25  <=>  g_max > -0.25 * ||x||
    const bool replace = fbest > (-0.25f * sqrtf(sumsq));
    const unsigned long long need_x = __ballot(!replace); // almost always 0

    float* __restrict__ ob = out + (size_t)b * C_DIM * HW;
    const float* __restrict__ drow = dict + (size_t)fidx * C_DIM;

    const int c0 = wv * NROWS;   // wave w writes channels [64w, 64w+64)
#pragma unroll 8
    for (int c = c0; c < c0 + NROWS; ++c) {
        float v = drow[c];             // per-lane gather, L2-hot (dict = 1 MB)
        if (need_x) {
            float xv = xb[(size_t)c * HW + pix];
            if (!replace) v = xv;
        }
        ob[(size_t)c * HW + pix] = v;  // coalesced store
    }
}

extern "C" void kernel_launch(void* const* d_in, const int* in_sizes, int n_in,
                              void* d_out, int out_size, void* d_ws, size_t ws_size,
                              hipStream_t stream) {
    const float* x    = (const float*)d_in[0];
    const float* dict = (const float*)d_in[1];
    float* out        = (float*)d_out;
    float* inv_norm   = (float*)d_ws;  // 512 floats of scratch

    dict_inv_norm<<<N_DICT, 64, 0, stream>>>(dict, inv_norm);
    negdict_main<<<1024, 512, 0, stream>>>(x, dict, inv_norm, out);
}

// Round 3
// 1556.307 us; speedup vs baseline: 1.6359x; 1.0640x over previous
//
#include <hip/hip_runtime.h>
#include <math.h>

#define C_DIM  512   // channels (K of the dot product)
#define N_DICT 512   // dictionary rows
#define HW     4096  // 64*64 pixels per image

// inv_norm[n] = 1 / sqrt(sum_c dict[n][c]^2)  -- fp32, sqrt+div precision
__global__ __launch_bounds__(64) void dict_inv_norm(const float* __restrict__ dict,
                                                    float* __restrict__ inv_norm) {
    const int n = blockIdx.x;
    const int lane = threadIdx.x;
    const float* row = dict + n * C_DIM;
    float s = 0.f;
#pragma unroll
    for (int j = 0; j < C_DIM / 64; ++j) {
        float v = row[j * 64 + lane];
        s = fmaf(v, v, s);
    }
#pragma unroll
    for (int off = 32; off > 0; off >>= 1)
        s += __shfl_down(s, off, 64);
    if (lane == 0) inv_norm[n] = 1.0f / sqrtf(s);
}

// Rounds 1-2 post-mortem: acc[] arrays were never promoted to registers
// (VGPR_Count 88/56, FETCH 93/103 GB of scratch traffic). Fix: NAMED scalar
// accumulators via macro expansion -- cannot be demoted to scratch.
// Block = 1024 thr = 16 waves over one 64-pixel group; wave w owns dict rows
// [32w, 32w+32) -> 32 named fp32 accs/lane. lane = pixel -> coalesced x loads;
// dict rows wave-uniform -> s_load broadcast into v_fmac_f32.

#define ACCS(F) F(0) F(1) F(2) F(3) F(4) F(5) F(6) F(7) \
                F(8) F(9) F(10) F(11) F(12) F(13) F(14) F(15) \
                F(16) F(17) F(18) F(19) F(20) F(21) F(22) F(23) \
                F(24) F(25) F(26) F(27) F(28) F(29) F(30) F(31)

#define DECL_ACC(i) float acc##i = 0.f;

#define ROW_FMA(i) { const float* __restrict__ dr = dbase + (size_t)(i) * C_DIM; \
    acc##i = fmaf(dr[0], xk0, acc##i); \
    acc##i = fmaf(dr[1], xk1, acc##i); \
    acc##i = fmaf(dr[2], xk2, acc##i); \
    acc##i = fmaf(dr[3], xk3, acc##i); \
    acc##i = fmaf(dr[4], xk4, acc##i); \
    acc##i = fmaf(dr[5], xk5, acc##i); \
    acc##i = fmaf(dr[6], xk6, acc##i); \
    acc##i = fmaf(dr[7], xk7, acc##i); }

#define ARGMAX(i) { float s = acc##i * invn[i]; \
    if (s > best) { best = s; bestn = n0 + (i); } }

__global__ __launch_bounds__(1024, 4) void negdict_main(const float* __restrict__ x,
                                                        const float* __restrict__ dict,
                                                        const float* __restrict__ inv_norm,
                                                        float* __restrict__ out) {
    const int pg   = blockIdx.x;          // 0..1023
    const int b    = pg >> 6;             // batch
    const int pix0 = (pg & 63) << 6;      // pixel group base within image
    const int lane = (int)(threadIdx.x & 63);
    const int wv   = __builtin_amdgcn_readfirstlane((int)(threadIdx.x >> 6)); // 0..15 uniform
    const int pix  = pix0 + lane;
    const int n0   = wv * 32;

    const float* __restrict__ xb = x + (size_t)b * C_DIM * HW; // [C][HW]

    ACCS(DECL_ACC)
    float sumsq = 0.f;

    for (int kc = 0; kc < C_DIM; kc += 8) {
        const float* __restrict__ xp = xb + (size_t)kc * HW + pix;
        float xk0 = xp[0 * HW];
        float xk1 = xp[1 * HW];
        float xk2 = xp[2 * HW];
        float xk3 = xp[3 * HW];
        float xk4 = xp[4 * HW];
        float xk5 = xp[5 * HW];
        float xk6 = xp[6 * HW];
        float xk7 = xp[7 * HW];
        sumsq = fmaf(xk0, xk0, sumsq);
        sumsq = fmaf(xk1, xk1, sumsq);
        sumsq = fmaf(xk2, xk2, sumsq);
        sumsq = fmaf(xk3, xk3, sumsq);
        sumsq = fmaf(xk4, xk4, sumsq);
        sumsq = fmaf(xk5, xk5, sumsq);
        sumsq = fmaf(xk6, xk6, sumsq);
        sumsq = fmaf(xk7, xk7, sumsq);

        const float* __restrict__ dbase = dict + (size_t)n0 * C_DIM + kc; // uniform
        ACCS(ROW_FMA)
    }

    // per-wave argmax over its 32 rows (ascending i, strict > => first-index ties like np.argmin)
    const float* __restrict__ invn = inv_norm + n0; // uniform s_loads
    float best = -3.0e38f;
    int   bestn = n0;
    ACCS(ARGMAX)

    // cross-wave combine (n ranges ascend with wave id -> tie keeps lowest n)
    __shared__ float ls_best[16][64];
    __shared__ int   ls_idx[16][64];
    ls_best[wv][lane] = best;
    ls_idx[wv][lane]  = bestn;
    __syncthreads();

    float fbest = ls_best[0][lane];
    int   fidx  = ls_idx[0][lane];
#pragma unroll
    for (int q = 1; q < 16; ++q) {
        float v  = ls_best[q][lane];
        int   id = ls_idx[q][lane];
        if (v > fbest) { fbest = v; fidx = id; }
    }

    // apm < 0.625  <=>  sim_max > -0.25  <=>  g_max > -0.25 * ||x||
    const bool replace = fbest > (-0.25f * sqrtf(sumsq));
    const unsigned long long need_x = __ballot(!replace); // almost always 0

    float* __restrict__ ob = out + (size_t)b * C_DIM * HW;
    const float* __restrict__ drow = dict + (size_t)fidx * C_DIM;

    const int c0 = wv * 32;   // wave w writes channels [32w, 32w+32)
#pragma unroll 8
    for (int c = c0; c < c0 + 32; ++c) {
        float v = drow[c];             // per-lane gather, L2-hot (dict = 1 MB)
        if (need_x) {
            float xv = xb[(size_t)c * HW + pix];
            if (!replace) v = xv;
        }
        ob[(size_t)c * HW + pix] = v;  // coalesced store
    }
}

extern "C" void kernel_launch(void* const* d_in, const int* in_sizes, int n_in,
                              void* d_out, int out_size, void* d_ws, size_t ws_size,
                              hipStream_t stream) {
    const float* x    = (const float*)d_in[0];
    const float* dict = (const float*)d_in[1];
    float* out        = (float*)d_out;
    float* inv_norm   = (float*)d_ws;  // 512 floats of scratch

    dict_inv_norm<<<N_DICT, 64, 0, stream>>>(dict, inv_norm);
    negdict_main<<<1024, 1024, 0, stream>>>(x, dict, inv_norm, out);
}